// Round 1
// 378.059 us; speedup vs baseline: 1.3688x; 1.3688x over previous
//
#include <hip/hip_runtime.h>
#include <hip/hip_bf16.h>

#define N_NODES 50000
#define DIM 128
#define N_GRAPHS 64
#define E_RAW 800000
#define E_TOT 850000
#define E_CAP 1200000   // >= E_TOT + 3*N_NODES (pad-to-4) + slack
#define NEG_SLOPE 0.2f

typedef unsigned int uint;
typedef unsigned short ushort;
typedef float v2f __attribute__((ext_vector_type(2)));
typedef short bf16x8 __attribute__((ext_vector_type(8)));
typedef float f32x4 __attribute__((ext_vector_type(4)));

// Column permutation pi (storage position -> logical feature), fixed by the
// MFMA C/D fragment layout (col = lane&15, row = (lane>>4)*4+reg):
//   storage ushort q in [0,64) holds logical cols ( (q>>2)+32*(q&3),  +16 ).
//   i.e. bf16/fp8 position p: pi(p) = (p>>3) + 32*((p>>1)&3) + 16*(p&1)
// Absorbed by permuting: W K-rows (layers 1-2), bias gather, Wf gather.
__device__ __forceinline__ int pi_pos(int p) {
    return (p >> 3) + 32 * ((p >> 1) & 3) + 16 * (p & 1);
}

__device__ __forceinline__ ushort f2bf(float f) {
    uint u = __float_as_uint(f);
    u += 0x7fffu + ((u >> 16) & 1u);      // RNE
    return (ushort)(u >> 16);
}

// ---------- init: counters + pooled only ----------
__global__ void init_kernel(int* deg, int* fillc, float* pooled) {
    int i = blockIdx.x * blockDim.x + threadIdx.x;
    if (i < N_NODES) { deg[i] = 0; fillc[i] = 0; }
    if (i < N_GRAPHS * DIM) pooled[i] = 0.f;
}

// ---------- layer-0 input fp32 -> bf16 (natural order) ----------
__global__ void x2bf_kernel(const float* __restrict__ x, ushort* __restrict__ xb) {
    int i = blockIdx.x * blockDim.x + threadIdx.x;
    if (i >= N_NODES * DIM / 4) return;
    float4 v = ((const float4*)x)[i];
    ushort4 o;
    o.x = f2bf(v.x); o.y = f2bf(v.y); o.z = f2bf(v.z); o.w = f2bf(v.w);
    ((ushort4*)xb)[i] = o;
}

// ---------- pack W into per-lane MFMA B-fragment layout (bf16) ----------
// chunk (ks,nt): lane l, elem j  =  W[klogical][nt*16 + (l&15)],
//   kp = ks*32 + (l>>4)*8 + j ;  klogical = kp (layer 0) else pi(kp)
__global__ void wprep_kernel(const float* __restrict__ Ws, ushort* __restrict__ Wfrag) {
    int t = blockIdx.x * blockDim.x + threadIdx.x;
    if (t >= 3 * 32 * 64) return;
    int l = t >> 11;
    int rem = t & 2047;
    int chunk = rem >> 6, lane = rem & 63;
    int ks = chunk >> 3, nt = chunk & 7;
    int cc = lane & 15, gg = lane >> 4;
    const float* W = Ws + (size_t)l * DIM * DIM;
    ushort o[8];
#pragma unroll
    for (int j = 0; j < 8; ++j) {
        int kp = ks * 32 + gg * 8 + j;
        int kl = (l == 0) ? kp : pi_pos(kp);
        o[j] = f2bf(W[kl * DIM + nt * 16 + cc]);
    }
#pragma unroll
    for (int j = 0; j < 8; ++j) Wfrag[(size_t)t * 8 + j] = o[j];
}

// ---------- CSR build (dst-sorted, segments padded to multiple of 4) ----------
__global__ void count_kernel(const int* __restrict__ ei, int* __restrict__ deg) {
    int e = blockIdx.x * blockDim.x + threadIdx.x;
    if (e >= E_TOT) return;
    int dst = (e < E_RAW) ? ei[E_RAW + e] : (e - E_RAW);
    atomicAdd(&deg[dst], 1);
}

__global__ void scan1_kernel(const int* __restrict__ deg, int* __restrict__ excl,
                             int* __restrict__ blksum, int n) {
    __shared__ int lds[256];
    int t = threadIdx.x;
    int i = blockIdx.x * 256 + t;
    int v = (i < n) ? ((deg[i] + 3) & ~3) : 0;   // pad degree to multiple of 4
    lds[t] = v;
    __syncthreads();
    int incl = v;
    for (int off = 1; off < 256; off <<= 1) {
        int y = (t >= off) ? lds[t - off] : 0;
        __syncthreads();
        incl += y;
        lds[t] = incl;
        __syncthreads();
    }
    if (i < n) excl[i] = incl - v;
    if (t == 255) blksum[blockIdx.x] = incl;
}

__global__ void scan2_kernel(int* __restrict__ blksum, int* __restrict__ row_ptr, int nblk) {
    __shared__ int lds[256];
    int t = threadIdx.x;
    int v = (t < nblk) ? blksum[t] : 0;
    lds[t] = v;
    __syncthreads();
    int incl = v;
    for (int off = 1; off < 256; off <<= 1) {
        int y = (t >= off) ? lds[t - off] : 0;
        __syncthreads();
        incl += y;
        lds[t] = incl;
        __syncthreads();
    }
    if (t < nblk) blksum[t] = incl - v;
    if (t == nblk - 1) row_ptr[N_NODES] = incl;
}

__global__ void scan3_kernel(int* __restrict__ row_ptr, const int* __restrict__ blksum, int n) {
    int i = blockIdx.x * blockDim.x + threadIdx.x;
    if (i < n) row_ptr[i] += blksum[i >> 8];
}

// write -1 into the <=3 pad slots of each node's segment
__global__ void pad_kernel(const int* __restrict__ deg, const int* __restrict__ row_ptr,
                           int* __restrict__ csr_src) {
    int i = blockIdx.x * blockDim.x + threadIdx.x;
    if (i >= N_NODES) return;
    int d = deg[i];
    int pd = (d + 3) & ~3;
    int base = row_ptr[i];
    for (int k = d; k < pd; ++k) csr_src[base + k] = -1;
}

__global__ void fill_kernel(const int* __restrict__ ei, const int* __restrict__ row_ptr,
                            int* __restrict__ fillc, int* __restrict__ csr_src) {
    int e = blockIdx.x * blockDim.x + threadIdx.x;
    if (e >= E_TOT) return;
    int src, dst;
    if (e < E_RAW) { src = ei[e]; dst = ei[E_RAW + e]; }
    else           { src = dst = e - E_RAW; }
    int slot = row_ptr[dst] + atomicAdd(&fillc[dst], 1);
    csr_src[slot] = src;
}

// ---------- MFMA GEMM + fused attention dots; H packed fp8 e4m3 (pi order) ----
// No LDS, no barriers. Per wave: 16 rows x 128 cols, 32 mfma_f32_16x16x32_bf16.
// A frags: one dwordx4/lane from bf16 X. B frags: one dwordx4/lane from the
// pre-packed Wfrag (32 KB/layer, L1-resident).
__global__ __launch_bounds__(256) void gemm_mfma_kernel(
    const ushort* __restrict__ Xb, const ushort* __restrict__ Wfrag,
    const float* __restrict__ asrc, const float* __restrict__ adst,
    uint* __restrict__ Hb, float* __restrict__ s1, float* __restrict__ s2, int nrows) {
    int wv = threadIdx.x >> 6;
    int lane = threadIdx.x & 63;
    int c = lane & 15, g = lane >> 4;
    int row0 = blockIdx.x * 64 + wv * 16;

    int arow = row0 + c;
    if (arow >= nrows) arow = nrows - 1;           // tail clamp (writes guarded)
    const ushort* xrow = Xb + (size_t)arow * DIM;

    f32x4 acc[8];
#pragma unroll
    for (int nt = 0; nt < 8; ++nt) acc[nt] = (f32x4)(0.f);

#pragma unroll
    for (int ks = 0; ks < 4; ++ks) {
        bf16x8 afrag = *(const bf16x8*)(xrow + ks * 32 + g * 8);
#pragma unroll
        for (int nt = 0; nt < 8; ++nt) {
            bf16x8 bfrag = *(const bf16x8*)(Wfrag + ((size_t)(ks * 8 + nt) * 64 + lane) * 8);
            acc[nt] = __builtin_amdgcn_mfma_f32_16x16x32_bf16(afrag, bfrag, acc[nt], 0, 0, 0);
        }
    }

    // attention-dot coefficients at this lane's logical cols (c + 16*nt)
    float a1[8], a2[8];
#pragma unroll
    for (int nt = 0; nt < 8; ++nt) { a1[nt] = asrc[c + 16 * nt]; a2[nt] = adst[c + 16 * nt]; }

#pragma unroll
    for (int r = 0; r < 4; ++r) {
        int outrow = row0 + g * 4 + r;
        bool valid = outrow < nrows;
        if (valid) {
            int w0 = __builtin_amdgcn_cvt_pk_fp8_f32(acc[0][r], acc[1][r], 0, false);
            w0     = __builtin_amdgcn_cvt_pk_fp8_f32(acc[2][r], acc[3][r], w0, true);
            int w1 = __builtin_amdgcn_cvt_pk_fp8_f32(acc[4][r], acc[5][r], 0, false);
            w1     = __builtin_amdgcn_cvt_pk_fp8_f32(acc[6][r], acc[7][r], w1, true);
            *(uint2*)&Hb[(size_t)outrow * 32 + c * 2] = make_uint2((uint)w0, (uint)w1);
        }
        float p1 = 0.f, p2 = 0.f;
#pragma unroll
        for (int nt = 0; nt < 8; ++nt) {
            p1 = fmaf(acc[nt][r], a1[nt], p1);
            p2 = fmaf(acc[nt][r], a2[nt], p2);
        }
#pragma unroll
        for (int m = 1; m < 16; m <<= 1) { p1 += __shfl_xor(p1, m); p2 += __shfl_xor(p2, m); }
        if (c == 0 && valid) { s1[outrow] = p1; s2[outrow] = p2; }
    }
}

// ---------- fused softmax + aggregation: one wave per EIGHT dst nodes ----------
// Inner loop unchanged (one contiguous 128 B fp8 row per gather). Output node
// features now written as bf16 (pi order) for the next layer's MFMA GEMM.
__global__ __launch_bounds__(256) void agg_kernel(
    const ushort* __restrict__ Hb16, const int* __restrict__ csr_src,
    const int* __restrict__ row_ptr, const float* __restrict__ s1,
    const float* __restrict__ s2n, const float* __restrict__ bias,
    ushort* __restrict__ Xout, const int* __restrict__ batch,
    float* __restrict__ pooled, int pool_flag, int ngroups) {
    int gw = (blockIdx.x * blockDim.x + threadIdx.x) >> 6;
    int lane = threadIdx.x & 63;
    if (gw >= ngroups) return;
    int node0 = gw * 8;

    int4 rpa = *(const int4*)&row_ptr[node0];
    int4 rpb = *(const int4*)&row_ptr[node0 + 4];
    int rp8 = row_ptr[node0 + 8];
    int rp[9] = {rpa.x, rpa.y, rpa.z, rpa.w, rpb.x, rpb.y, rpb.z, rpb.w, rp8};
    float4 s2qa = *(const float4*)&s2n[node0];
    float4 s2qb = *(const float4*)&s2n[node0 + 4];
    float s2a[8] = {s2qa.x, s2qa.y, s2qa.z, s2qa.w, s2qb.x, s2qb.y, s2qb.z, s2qb.w};
    // bias gather in pi space: lane's pair = logical cols ((lane>>2)+32*(lane&3), +16)
    int cc = lane >> 2, ii = lane & 3;
    float2 b2;
    b2.x = bias[cc + 32 * ii];
    b2.y = bias[cc + 32 * ii + 16];
    int ba[8] = {0, 0, 0, 0, 0, 0, 0, 0};
    if (pool_flag) {
        int4 bqa = *(const int4*)&batch[node0];
        int4 bqb = *(const int4*)&batch[node0 + 4];
        ba[0] = bqa.x; ba[1] = bqa.y; ba[2] = bqa.z; ba[3] = bqa.w;
        ba[4] = bqb.x; ba[5] = bqb.y; ba[6] = bqb.z; ba[7] = bqb.w;
    }

#pragma unroll
    for (int k = 0; k < 8; ++k) {
        int beg = rp[k], end = rp[k + 1];
        float s2v = s2a[k];
        float2 acc = make_float2(0.f, 0.f);
        float wsum = 0.f;

        for (int s = beg; s < end; s += 8) {
            int4 a = *(const int4*)&csr_src[s];
            bool vb = (s + 4) < end;                     // wave-uniform
            int4 b = vb ? *(const int4*)&csr_src[s + 4] : make_int4(-1, -1, -1, -1);
            int sn[8] = {a.x, a.y, a.z, a.w, b.x, b.y, b.z, b.w};
            ushort hv[8];
#pragma unroll
            for (int j = 0; j < 8; ++j) {
                int r = (sn[j] < 0) ? 0 : sn[j];
                hv[j] = Hb16[(size_t)r * 64 + lane];
            }
            float w[8];
#pragma unroll
            for (int j = 0; j < 8; ++j) {
                int r = (sn[j] < 0) ? 0 : sn[j];
                float al = s1[r] + s2v;
                al = (al > 0.f) ? al : NEG_SLOPE * al;
                float e = __expf(al);
                w[j] = (sn[j] < 0) ? 0.f : e;
                wsum += w[j];
            }
#pragma unroll
            for (int j = 0; j < 8; ++j) {
                v2f f = __builtin_amdgcn_cvt_pk_f32_fp8((int)hv[j], false);
                acc.x = fmaf(w[j], f.x, acc.x);
                acc.y = fmaf(w[j], f.y, acc.y);
            }
        }

        float inv = 1.f / (wsum + 1e-16f);
        acc.x = fmaxf(fmaf(acc.x, inv, b2.x), 0.f);
        acc.y = fmaxf(fmaf(acc.y, inv, b2.y), 0.f);
        if (pool_flag) {
            atomicAdd(&pooled[ba[k] * DIM + 2 * lane], acc.x);
            atomicAdd(&pooled[ba[k] * DIM + 2 * lane + 1], acc.y);
        } else {
            ushort2 hb;
            hb.x = f2bf(acc.x);
            hb.y = f2bf(acc.y);
            ((ushort2*)Xout)[(size_t)(node0 + k) * 64 + lane] = hb;
        }
    }
}

__global__ void final_kernel(const float* __restrict__ pooled, const float* __restrict__ Wf,
                             const float* __restrict__ bf, float* __restrict__ y) {
    int wid = (blockIdx.x * blockDim.x + threadIdx.x) >> 6;
    int lane = threadIdx.x & 63;
    if (wid >= N_GRAPHS) return;
    float2 p = *(const float2*)&pooled[wid * DIM + 2 * lane];
    // pooled is in pi order -> gather Wf at logical cols
    int cc = lane >> 2, ii = lane & 3;
    float wx = Wf[cc + 32 * ii];
    float wy = Wf[cc + 32 * ii + 16];
    float v = p.x * wx + p.y * wy;
    for (int off = 32; off; off >>= 1) v += __shfl_down(v, off);
    if (lane == 0) y[wid] = v + bf[0];
}

extern "C" void kernel_launch(void* const* d_in, const int* in_sizes, int n_in,
                              void* d_out, int out_size, void* d_ws, size_t ws_size,
                              hipStream_t stream) {
    const float* x       = (const float*)d_in[0];
    const int*   ei      = (const int*)d_in[1];
    const int*   batch   = (const int*)d_in[2];
    const float* Ws      = (const float*)d_in[3];
    const float* att_src = (const float*)d_in[4];
    const float* att_dst = (const float*)d_in[5];
    const float* biases  = (const float*)d_in[6];
    const float* Wf      = (const float*)d_in[7];
    const float* bf      = (const float*)d_in[8];
    float* y = (float*)d_out;

    char* p = (char*)d_ws;
    auto alloc = [&](size_t bytes) -> void* {
        void* r = (void*)p;
        p += (bytes + 255) & ~(size_t)255;
        return r;
    };
    ushort* xC     = (ushort*)alloc((size_t)(N_NODES + 64) * DIM * 2);  // bf16
    ushort* xA     = (ushort*)alloc((size_t)(N_NODES + 64) * DIM * 2);  // bf16
    uint*   Hb     = (uint*)alloc((size_t)N_NODES * 32 * 4);   // fp8 e4m3, 128 B/row
    ushort* Wfrag  = (ushort*)alloc((size_t)3 * 32 * 64 * 8 * 2);
    int*   csr_src = (int*)alloc((size_t)E_CAP * 4);
    int*   deg     = (int*)alloc((size_t)N_NODES * 4);
    int*   fillc   = (int*)alloc((size_t)N_NODES * 4);
    int*   row_ptr = (int*)alloc((size_t)(N_NODES + 16) * 4);
    int*   blksum  = (int*)alloc(256 * 4);
    float* s1      = (float*)alloc((size_t)N_NODES * 4);
    float* s2      = (float*)alloc((size_t)(N_NODES + 8) * 4);
    float* pooled  = (float*)alloc((size_t)N_GRAPHS * DIM * 4);

    const int BN = 256;
    const int gN   = (N_NODES + BN - 1) / BN;
    const int gE   = (E_TOT + BN - 1) / BN;
    const int ngroups = N_NODES / 8;                 // 6250, exact
    const int gAGG = (ngroups * 64 + BN - 1) / BN;   // one wave per 8 nodes
    const int nblk = gN;
    const int gCVT = (N_NODES * DIM / 4 + BN - 1) / BN;
    const int gGEMM = (N_NODES + 63) / 64;

    init_kernel<<<gN, BN, 0, stream>>>(deg, fillc, pooled);
    x2bf_kernel<<<gCVT, BN, 0, stream>>>(x, xC);
    wprep_kernel<<<(3 * 32 * 64 + BN - 1) / BN, BN, 0, stream>>>(Ws, Wfrag);
    count_kernel<<<gE, BN, 0, stream>>>(ei, deg);
    scan1_kernel<<<nblk, BN, 0, stream>>>(deg, row_ptr, blksum, N_NODES);
    scan2_kernel<<<1, BN, 0, stream>>>(blksum, row_ptr, nblk);
    scan3_kernel<<<gN, BN, 0, stream>>>(row_ptr, blksum, N_NODES);
    pad_kernel<<<gN, BN, 0, stream>>>(deg, row_ptr, csr_src);
    fill_kernel<<<gE, BN, 0, stream>>>(ei, row_ptr, fillc, csr_src);

    const ushort* xin = xC;
    ushort* xout = xA;
    for (int l = 0; l < 3; ++l) {
        const ushort* Wf_l = Wfrag + (size_t)l * 32 * 64 * 8;
        const float* as = att_src + (size_t)l * DIM;
        const float* ad = att_dst + (size_t)l * DIM;
        const float* b  = biases + (size_t)l * DIM;

        gemm_mfma_kernel<<<gGEMM, BN, 0, stream>>>(xin, Wf_l, as, ad, Hb, s1, s2, N_NODES);
        agg_kernel<<<gAGG, BN, 0, stream>>>((const ushort*)Hb, csr_src, row_ptr, s1, s2, b,
                                            xout, batch, pooled,
                                            (l == 2) ? 1 : 0, ngroups);
        xin = xout;
        xout = (l == 0) ? xC : xA;   // ping-pong: xC free after layer-0 GEMM
    }

    final_kernel<<<(N_GRAPHS * 64 + BN - 1) / BN, BN, 0, stream>>>(pooled, Wf, bf, y);
    (void)ws_size; (void)n_in; (void)in_sizes; (void)out_size;
}